// Round 11
// baseline (135.230 us; speedup 1.0000x reference)
//
#include <hip/hip_runtime.h>
#include <math.h>

#define N_ROWS 4096
#define DIM    128
#define A_LAB  512
#define INV_TAU 14.285714285714286f
#define C_EXP   20.609929155556620f   // INV_TAU * log2(e)

typedef __attribute__((ext_vector_type(8))) short short8;   // 8 bf16 (4 VGPRs)
typedef __attribute__((ext_vector_type(4))) float f32x4;    // MFMA C/D frag (16x16)
typedef __attribute__((ext_vector_type(4))) int i32x4;      // i8 MFMA A/B frag
typedef __attribute__((ext_vector_type(16))) int i32x16;    // i8 MFMA C/D frag (32x32)

// ---------------- workspace layout (bytes) ----------------
// zbf   u16 [8192*128]   @ 0          (2,097,152)  FRAG-MAJOR (see k_norm_pack)
// labs8 i8  [4096*512]   @ 2,097,152  (2,097,152)  FRAG-MAJOR (see k_norm_pack)
// s     i32 [4096]       @ 4,194,304  (16,384)
// part  f32 [3*4096]     @ 4,210,688  (49,152)     atomically accumulated

__device__ __forceinline__ unsigned short f2bf(float f) {
  unsigned int u = __builtin_bit_cast(unsigned int, f);
  u += 0x7fffu + ((u >> 16) & 1u);            // round-to-nearest-even
  return (unsigned short)(u >> 16);
}

// ------------ kernel 1: L2-normalize (-> bf16, frag-major) + labels -> i8 frag-major ------------
__global__ __launch_bounds__(256) void k_norm_pack(
    const float* __restrict__ z1, const float* __restrict__ z2,
    const int* __restrict__ labels,
    unsigned int* __restrict__ zbf, uint2* __restrict__ labs8,
    int* __restrict__ s, float* __restrict__ part, float* __restrict__ out)
{
  {
    const int idx = blockIdx.x * 256 + threadIdx.x;
    if (idx < 3 * 4096) part[idx] = 0.0f;
    if (idx == 0) out[0] = 0.0f;
  }
  const int wave = threadIdx.x >> 6, lane = threadIdx.x & 63;
  const int r = blockIdx.x * 4 + wave;         // 0..8191
  const float* src = (r < N_ROWS) ? (z1 + (size_t)r * DIM)
                                  : (z2 + (size_t)(r - N_ROWS) * DIM);
  float2 x = ((const float2*)src)[lane];
  float ss = x.x * x.x + x.y * x.y;
  #pragma unroll
  for (int off = 32; off > 0; off >>= 1) ss += __shfl_xor(ss, off);
  const float inv = 1.0f / fmaxf(sqrtf(ss), 1e-12f);
  const unsigned int lo = f2bf(x.x * inv);
  const unsigned int hi = f2bf(x.y * inv);
  {
    const int u = lane >> 2, p = lane & 3;
    const int kf = u >> 2, quad = u & 3;
    const int g = r >> 4;
    zbf[(size_t)(((g * 4 + kf) * 64) + ((r & 15) + (quad << 4))) * 4 + p] = (hi << 16) | lo;
  }

  if (r < N_ROWS) {
    const int4* lp = (const int4*)(labels + (size_t)r * A_LAB);
    const int4 a = lp[2 * lane], b = lp[2 * lane + 1];
    const unsigned int w0 = (unsigned int)(a.x != 0)       | ((unsigned int)(a.y != 0) << 8)
                          | ((unsigned int)(a.z != 0) << 16) | ((unsigned int)(a.w != 0) << 24);
    const unsigned int w1 = (unsigned int)(b.x != 0)       | ((unsigned int)(b.y != 0) << 8)
                          | ((unsigned int)(b.z != 0) << 16) | ((unsigned int)(b.w != 0) << 24);
    uint2 v; v.x = w0; v.y = w1;
    const int ul = lane >> 1, hp = lane & 1;
    const int ks = ul >> 1, h = ul & 1;
    const int g = r >> 5;
    labs8[(size_t)(((g * 16 + ks) * 64) + ((r & 31) + (h << 5))) * 2 + hp] = v;
    int cnt = __popc(w0) + __popc(w1);
    #pragma unroll
    for (int off = 32; off > 0; off >>= 1) cnt += __shfl_xor(cnt, off);
    if (lane == 0) s[r] = cnt;
  }
}

// ------------ kernel 2: FUSED jaccard + sim + masked-softmax, 64x64 wave tiles ------------
// Block (bi,bj): anchors [128bi..+128) x cols {[128bj..+128), [4096+128bj..+128)}.
// 256 threads = 2x2 waves; wave tile 64x64 in BOTH phases for max MACs/byte:
//   jac: per ks, 2 A + 2 B loads -> 4 MFMAs (32x32x32 i8)
//   sim: per kf, 4 A + 4 B loads -> 16 MFMAs (16x16x32 bf16)
// Frag-major global-direct loads (1 coalesced KB/frag, L2-resident); only LDS
// is the 2 KB pmL pos-mask; exactly ONE __syncthreads.
__global__ __launch_bounds__(256, 3) void k_fused(
    const unsigned char* __restrict__ labs8, const int* __restrict__ s,
    const unsigned short* __restrict__ zbf, float* __restrict__ part)
{
  __shared__ unsigned int pmL[128 * 4];       // pos-bits: [local row][col word]
  const int tid = threadIdx.x;
  const int ibase = blockIdx.x * 128, jbase = blockIdx.y * 128;
  const int wave = tid >> 6, lane = tid & 63;
  const int wr = wave >> 1, wc = wave & 1;    // 2x2 wave grid
  const bool diag = (ibase == jbase);
  const char* gl = (const char*)labs8;
  const char* gz = (const char*)zbf;

  // ---------------- phase J: jaccard, wave tile 64x64 ----------------
  const int jwr = wr * 64, jwc = wc * 64;
  const int col32 = lane & 31, h = lane >> 5;

  const int s3i = 3 * s[ibase + jwr + lane];  // this wave's 64 rows
  const int s3j = 3 * s[jbase + jwc + lane];  // this wave's 64 cols

  i32x16 jacc[2][2];
  #pragma unroll
  for (int rt = 0; rt < 2; ++rt)
    #pragma unroll
    for (int nt = 0; nt < 2; ++nt)
      #pragma unroll
      for (int e = 0; e < 16; ++e) jacc[rt][nt][e] = 0;

  const int gI = (ibase + jwr) >> 5;          // 32-row groups gI, gI+1
  const int gJ = (jbase + jwc) >> 5;
  #pragma unroll
  for (int ks = 0; ks < 16; ++ks) {
    i32x4 a[2], b[2];
    #pragma unroll
    for (int rt = 0; rt < 2; ++rt)
      a[rt] = *(const i32x4*)(gl + (size_t)(((gI + rt) * 16 + ks) * 64 + lane) * 16);
    #pragma unroll
    for (int nt = 0; nt < 2; ++nt)
      b[nt] = *(const i32x4*)(gl + (size_t)(((gJ + nt) * 16 + ks) * 64 + lane) * 16);
    #pragma unroll
    for (int rt = 0; rt < 2; ++rt)
      #pragma unroll
      for (int nt = 0; nt < 2; ++nt)
        jacc[rt][nt] = __builtin_amdgcn_mfma_i32_32x32x32_i8(a[rt], b[nt], jacc[rt][nt], 0, 0, 0);
  }

  // jac epilogue: threshold + ballot -> pmL (wave owns rows jwr..+64, words wc*2..+2)
  #pragma unroll
  for (int rt = 0; rt < 2; ++rt)
    #pragma unroll
    for (int nt = 0; nt < 2; ++nt) {
      const int wl = wc * 2 + nt;
      const int sj = __shfl(s3j, nt * 32 + col32);
      #pragma unroll
      for (int reg = 0; reg < 16; ++reg) {
        const int r0 = (reg & 3) + 8 * (reg >> 2);
        const int si = __shfl(s3i, rt * 32 + r0 + 4 * h);
        const bool pred = 13 * jacc[rt][nt][reg] >= si + sj;
        const unsigned long long bal = __ballot(pred);
        const int lr = jwr + rt * 32 + r0;
        if (lane == 0)      pmL[lr * 4 + wl]       = (unsigned int)bal;
        else if (lane == 1) pmL[(lr + 4) * 4 + wl] = (unsigned int)(bal >> 32);
      }
    }

  __syncthreads();   // the ONLY barrier: pmL visible to all waves

  // ---------------- phase S: similarity, wave tile 64 anchors x 64 cols x 2 halves ----------------
  const int col = lane & 15, quad = lane >> 4;
  const int swr = wr * 64, swc = wc * 64;
  const int gA = (ibase + swr) >> 4;             // 16-row groups gA..gA+3

  // this wave's 2 mask words per row (cols swc..swc+64), 16 rows/lane
  uint2 pw[4][4];
  #pragma unroll
  for (int rt = 0; rt < 4; ++rt)
    #pragma unroll
    for (int reg = 0; reg < 4; ++reg)
      pw[rt][reg] = *(const uint2*)&pmL[(swr + rt * 16 + quad * 4 + reg) * 4 + wc * 2];

  float lacc[4][4], Sacc[4][4], Pcnt[4][4];
  #pragma unroll
  for (int rt = 0; rt < 4; ++rt)
    #pragma unroll
    for (int reg = 0; reg < 4; ++reg) { lacc[rt][reg] = 0; Sacc[rt][reg] = 0; Pcnt[rt][reg] = 0; }

  #pragma unroll
  for (int half = 0; half < 2; ++half) {
    const int gB = (((half ? N_ROWS : 0) + jbase + swc) >> 4);
    f32x4 acc[4][4];
    #pragma unroll
    for (int rt = 0; rt < 4; ++rt)
      #pragma unroll
      for (int nt = 0; nt < 4; ++nt) acc[rt][nt] = (f32x4){0, 0, 0, 0};

    #pragma unroll
    for (int kf = 0; kf < 4; ++kf) {
      short8 a[4], b[4];
      #pragma unroll
      for (int rt = 0; rt < 4; ++rt)
        a[rt] = *(const short8*)(gz + (size_t)(((gA + rt) * 4 + kf) * 64 + lane) * 16);
      #pragma unroll
      for (int nt = 0; nt < 4; ++nt)
        b[nt] = *(const short8*)(gz + (size_t)(((gB + nt) * 4 + kf) * 64 + lane) * 16);
      #pragma unroll
      for (int rt = 0; rt < 4; ++rt)
        #pragma unroll
        for (int nt = 0; nt < 4; ++nt)
          acc[rt][nt] = __builtin_amdgcn_mfma_f32_16x16x32_bf16(a[rt], b[nt], acc[rt][nt], 0, 0, 0);
    }

    if (!diag) {
      // slim: same mask both halves, no self/aug; P via popcount at the end
      #pragma unroll
      for (int rt = 0; rt < 4; ++rt)
        #pragma unroll
        for (int nt = 0; nt < 4; ++nt) {
          const int bitpos = (nt & 1) * 16 + col;
          #pragma unroll
          for (int reg = 0; reg < 4; ++reg) {
            const unsigned int w = (nt >> 1) ? pw[rt][reg].y : pw[rt][reg].x;
            const float d = acc[rt][nt][reg];
            lacc[rt][reg] += exp2f(fmaf(d, C_EXP, -C_EXP));
            if ((w >> bitpos) & 1) Sacc[rt][reg] += d;
          }
        }
    } else {
      const bool left = (half == 0);
      #pragma unroll
      for (int rt = 0; rt < 4; ++rt)
        #pragma unroll
        for (int nt = 0; nt < 4; ++nt) {
          const int joff = swc + nt * 16 + col;    // 0..127 within tile
          const int jc = jbase + joff;
          const int bitpos = joff & 31;
          #pragma unroll
          for (int reg = 0; reg < 4; ++reg) {
            const int i = ibase + swr + rt * 16 + quad * 4 + reg;
            const unsigned int w = (nt >> 1) ? pw[rt][reg].y : pw[rt][reg].x;
            const float d = acc[rt][nt][reg];
            const bool bit = (w >> bitpos) & 1;
            const bool self = left && (jc == i);
            const bool pos = left ? (bit && !self) : (bit || (jc == i));
            const float e = exp2f(fmaf(d, C_EXP, -C_EXP));
            if (!self) lacc[rt][reg] += e;
            if (pos) { Sacc[rt][reg] += d; Pcnt[rt][reg] += 1.0f; }
          }
        }
    }
  }

  // ---- reduce across the 16 col-lanes, atomically accumulate per-anchor ----
  #pragma unroll
  for (int rt = 0; rt < 4; ++rt)
    #pragma unroll
    for (int reg = 0; reg < 4; ++reg) {
      float l = lacc[rt][reg], S = Sacc[rt][reg], P = Pcnt[rt][reg];
      #pragma unroll
      for (int m = 1; m < 16; m <<= 1) {
        l += __shfl_xor(l, m);
        S += __shfl_xor(S, m);
        if (diag) P += __shfl_xor(P, m);
      }
      if (col == 0) {
        const int i = ibase + swr + rt * 16 + quad * 4 + reg;
        if (!diag) {
          const uint2 w = pw[rt][reg];
          P = 2.0f * (float)(__popc(w.x) + __popc(w.y));
        }
        atomicAdd(&part[i], l);
        atomicAdd(&part[4096 + i], S);
        atomicAdd(&part[8192 + i], P);
      }
    }
}

// ---------------- kernel 3: per-anchor loss + atomic final reduce ----------------
__global__ __launch_bounds__(128) void k_loss(
    const float* __restrict__ part, float* __restrict__ out)
{
  const int a = blockIdx.x * 128 + threadIdx.x;   // 0..4095
  const float l = part[a];
  const float S = part[4096 + a];
  const float P = part[8192 + a];
  const float np = fmaxf(P, 1.0f);
  float v = INV_TAU + logf(l + 1e-8f) - (S * INV_TAU) / np;
  #pragma unroll
  for (int off = 32; off > 0; off >>= 1) v += __shfl_xor(v, off);
  __shared__ float ws2[2];
  const int wave = threadIdx.x >> 6, lane = threadIdx.x & 63;
  if (lane == 0) ws2[wave] = v;
  __syncthreads();
  if (threadIdx.x == 0) atomicAdd(out, (ws2[0] + ws2[1]) * (1.0f / (float)N_ROWS));
}

extern "C" void kernel_launch(void* const* d_in, const int* in_sizes, int n_in,
                              void* d_out, int out_size, void* d_ws, size_t ws_size,
                              hipStream_t stream) {
  const float* z1 = (const float*)d_in[0];
  const float* z2 = (const float*)d_in[1];
  const int* labels = (const int*)d_in[2];
  float* out = (float*)d_out;
  char* ws = (char*)d_ws;

  unsigned int* zbf    = (unsigned int*)(ws);
  uint2* labs8         = (uint2*)(ws + 2097152);
  int* s               = (int*)(ws + 4194304);
  float* part          = (float*)(ws + 4210688);

  hipLaunchKernelGGL(k_norm_pack, dim3(2048), dim3(256), 0, stream,
                     z1, z2, labels, zbf, labs8, s, part, out);
  hipLaunchKernelGGL(k_fused, dim3(32, 32), dim3(256), 0, stream,
                     (const unsigned char*)labs8, s, (const unsigned short*)zbf, part);
  hipLaunchKernelGGL(k_loss, dim3(32), dim3(128), 0, stream, part, out);
}

// Round 12
// 114.982 us; speedup vs baseline: 1.1761x; 1.1761x over previous
//
#include <hip/hip_runtime.h>
#include <math.h>

#define N_ROWS 4096
#define DIM    128
#define A_LAB  512
#define INV_TAU 14.285714285714286f
#define C_EXP   20.609929155556620f   // INV_TAU * log2(e)

typedef __attribute__((ext_vector_type(8))) short short8;   // 8 bf16 (4 VGPRs)
typedef __attribute__((ext_vector_type(4))) float f32x4;    // MFMA C/D frag (16x16)
typedef __attribute__((ext_vector_type(4))) int i32x4;      // i8 MFMA A/B frag
typedef __attribute__((ext_vector_type(16))) int i32x16;    // i8 MFMA C/D frag (32x32)

// ---------------- workspace layout (bytes) ----------------
// zbf   u16 [8192*128]   @ 0          (2,097,152)  FRAG-MAJOR (see k_norm_pack)
// labs8 i8  [4096*512]   @ 2,097,152  (2,097,152)  FRAG-MAJOR (see k_norm_pack)
// s     i32 [4096]       @ 4,194,304  (16,384)
// part  f32 [3*4096]     @ 4,210,688  (49,152)     atomically accumulated

__device__ __forceinline__ unsigned short f2bf(float f) {
  unsigned int u = __builtin_bit_cast(unsigned int, f);
  u += 0x7fffu + ((u >> 16) & 1u);            // round-to-nearest-even
  return (unsigned short)(u >> 16);
}

// ------------ kernel 1: L2-normalize (-> bf16, frag-major) + labels -> i8 frag-major ------------
__global__ __launch_bounds__(256) void k_norm_pack(
    const float* __restrict__ z1, const float* __restrict__ z2,
    const int* __restrict__ labels,
    unsigned int* __restrict__ zbf, uint2* __restrict__ labs8,
    int* __restrict__ s, float* __restrict__ part, float* __restrict__ out)
{
  {
    const int idx = blockIdx.x * 256 + threadIdx.x;
    if (idx < 3 * 4096) part[idx] = 0.0f;
    if (idx == 0) out[0] = 0.0f;
  }
  const int wave = threadIdx.x >> 6, lane = threadIdx.x & 63;
  const int r = blockIdx.x * 4 + wave;         // 0..8191
  const float* src = (r < N_ROWS) ? (z1 + (size_t)r * DIM)
                                  : (z2 + (size_t)(r - N_ROWS) * DIM);
  float2 x = ((const float2*)src)[lane];
  float ss = x.x * x.x + x.y * x.y;
  #pragma unroll
  for (int off = 32; off > 0; off >>= 1) ss += __shfl_xor(ss, off);
  const float inv = 1.0f / fmaxf(sqrtf(ss), 1e-12f);
  const unsigned int lo = f2bf(x.x * inv);
  const unsigned int hi = f2bf(x.y * inv);
  {
    const int u = lane >> 2, p = lane & 3;
    const int kf = u >> 2, quad = u & 3;
    const int g = r >> 4;
    zbf[(size_t)(((g * 4 + kf) * 64) + ((r & 15) + (quad << 4))) * 4 + p] = (hi << 16) | lo;
  }

  if (r < N_ROWS) {
    const int4* lp = (const int4*)(labels + (size_t)r * A_LAB);
    const int4 a = lp[2 * lane], b = lp[2 * lane + 1];
    const unsigned int w0 = (unsigned int)(a.x != 0)       | ((unsigned int)(a.y != 0) << 8)
                          | ((unsigned int)(a.z != 0) << 16) | ((unsigned int)(a.w != 0) << 24);
    const unsigned int w1 = (unsigned int)(b.x != 0)       | ((unsigned int)(b.y != 0) << 8)
                          | ((unsigned int)(b.z != 0) << 16) | ((unsigned int)(b.w != 0) << 24);
    uint2 v; v.x = w0; v.y = w1;
    const int ul = lane >> 1, hp = lane & 1;
    const int ks = ul >> 1, h = ul & 1;
    const int g = r >> 5;
    labs8[(size_t)(((g * 16 + ks) * 64) + ((r & 31) + (h << 5))) * 2 + hp] = v;
    int cnt = __popc(w0) + __popc(w1);
    #pragma unroll
    for (int off = 32; off > 0; off >>= 1) cnt += __shfl_xor(cnt, off);
    if (lane == 0) s[r] = cnt;
  }
}

// ------------ kernel 2: FUSED jaccard + sim + masked-softmax ------------
// 256 threads (4 waves), __launch_bounds__(256,2): VGPR cap 256 -> NO spill at
// the ~170-reg peak (R11's spill was the (256,3)->84-reg squeeze).
// Phase J: 2x2 waves, 64x64 tiles: per ks, 4 loads -> 4 MFMAs (i8 32x32x32).
// Phase S: wave = 32 anchor rows x 128 cols, as two sequential 64-col halves
//   (acc stays 32 regs); afr (32 regs) loaded ONCE, reused across all 4
//   (col-half x z-half) passes: per kf, 4 b-loads -> 8 MFMAs.
// Fragment traffic 544 KB/block vs R10's 928. One __syncthreads (pmL).
__global__ __launch_bounds__(256, 2) void k_fused(
    const unsigned char* __restrict__ labs8, const int* __restrict__ s,
    const unsigned short* __restrict__ zbf, float* __restrict__ part)
{
  __shared__ unsigned int pmL[128 * 4];       // pos-bits: [local row][col word]
  const int tid = threadIdx.x;
  const int ibase = blockIdx.x * 128, jbase = blockIdx.y * 128;
  const int wave = tid >> 6, lane = tid & 63;
  const int wr = wave >> 1, wc = wave & 1;    // 2x2 wave grid
  const bool diag = (ibase == jbase);
  const char* gl = (const char*)labs8;
  const char* gz = (const char*)zbf;

  // ---------------- phase J: jaccard, wave tile 64x64 ----------------
  const int jwr = wr * 64, jwc = wc * 64;
  const int col32 = lane & 31, h = lane >> 5;

  const int s3i = 3 * s[ibase + jwr + lane];  // this wave's 64 rows
  const int s3j = 3 * s[jbase + jwc + lane];  // this wave's 64 cols

  i32x16 jacc[2][2];
  #pragma unroll
  for (int rt = 0; rt < 2; ++rt)
    #pragma unroll
    for (int nt = 0; nt < 2; ++nt)
      #pragma unroll
      for (int e = 0; e < 16; ++e) jacc[rt][nt][e] = 0;

  const int gI = (ibase + jwr) >> 5;          // 32-row groups gI, gI+1
  const int gJ = (jbase + jwc) >> 5;
  #pragma unroll
  for (int ks = 0; ks < 16; ++ks) {
    i32x4 a[2], b[2];
    #pragma unroll
    for (int rt = 0; rt < 2; ++rt)
      a[rt] = *(const i32x4*)(gl + (size_t)(((gI + rt) * 16 + ks) * 64 + lane) * 16);
    #pragma unroll
    for (int nt = 0; nt < 2; ++nt)
      b[nt] = *(const i32x4*)(gl + (size_t)(((gJ + nt) * 16 + ks) * 64 + lane) * 16);
    #pragma unroll
    for (int rt = 0; rt < 2; ++rt)
      #pragma unroll
      for (int nt = 0; nt < 2; ++nt)
        jacc[rt][nt] = __builtin_amdgcn_mfma_i32_32x32x32_i8(a[rt], b[nt], jacc[rt][nt], 0, 0, 0);
  }

  // jac epilogue: threshold + ballot -> pmL (wave owns rows jwr..+64, words wc*2..+2)
  #pragma unroll
  for (int rt = 0; rt < 2; ++rt)
    #pragma unroll
    for (int nt = 0; nt < 2; ++nt) {
      const int wl = wc * 2 + nt;
      const int sj = __shfl(s3j, nt * 32 + col32);
      #pragma unroll
      for (int reg = 0; reg < 16; ++reg) {
        const int r0 = (reg & 3) + 8 * (reg >> 2);
        const int si = __shfl(s3i, rt * 32 + r0 + 4 * h);
        const bool pred = 13 * jacc[rt][nt][reg] >= si + sj;
        const unsigned long long bal = __ballot(pred);
        const int lr = jwr + rt * 32 + r0;
        if (lane == 0)      pmL[lr * 4 + wl]       = (unsigned int)bal;
        else if (lane == 1) pmL[(lr + 4) * 4 + wl] = (unsigned int)(bal >> 32);
      }
    }

  __syncthreads();   // the ONLY barrier: pmL visible to all waves

  // ---------------- phase S: wave = 32 rows x 128 cols x 2 z-halves ----------------
  const int col = lane & 15, quad = lane >> 4;
  const int swr = wave * 32;                     // this wave: rows [swr, swr+32)
  const int gA = (ibase + swr) >> 4;             // 16-row groups gA, gA+1

  short8 afr[2][4];                              // loaded once, reused 4x
  #pragma unroll
  for (int rt = 0; rt < 2; ++rt)
    #pragma unroll
    for (int kf = 0; kf < 4; ++kf)
      afr[rt][kf] = *(const short8*)(gz + (size_t)(((gA + rt) * 4 + kf) * 64 + lane) * 16);

  // full 128-col mask words for this wave's rows
  uint4 pw[2][4];
  #pragma unroll
  for (int rt = 0; rt < 2; ++rt)
    #pragma unroll
    for (int reg = 0; reg < 4; ++reg)
      pw[rt][reg] = *(const uint4*)&pmL[(swr + rt * 16 + quad * 4 + reg) * 4];

  float lacc[2][4], Sacc[2][4], Pcnt[2][4];
  #pragma unroll
  for (int rt = 0; rt < 2; ++rt)
    #pragma unroll
    for (int reg = 0; reg < 4; ++reg) { lacc[rt][reg] = 0; Sacc[rt][reg] = 0; Pcnt[rt][reg] = 0; }

  #pragma unroll
  for (int half = 0; half < 2; ++half) {
    #pragma unroll
    for (int ch = 0; ch < 2; ++ch) {             // 64-col halves
      const int gB = (((half ? N_ROWS : 0) + jbase + ch * 64) >> 4);
      f32x4 acc[2][4];
      #pragma unroll
      for (int rt = 0; rt < 2; ++rt)
        #pragma unroll
        for (int nt = 0; nt < 4; ++nt) acc[rt][nt] = (f32x4){0, 0, 0, 0};

      #pragma unroll
      for (int kf = 0; kf < 4; ++kf) {
        short8 b[4];
        #pragma unroll
        for (int nt = 0; nt < 4; ++nt)
          b[nt] = *(const short8*)(gz + (size_t)(((gB + nt) * 4 + kf) * 64 + lane) * 16);
        #pragma unroll
        for (int rt = 0; rt < 2; ++rt)
          #pragma unroll
          for (int nt = 0; nt < 4; ++nt)
            acc[rt][nt] = __builtin_amdgcn_mfma_f32_16x16x32_bf16(
                afr[rt][kf], b[nt], acc[rt][nt], 0, 0, 0);
      }

      if (!diag) {
        #pragma unroll
        for (int rt = 0; rt < 2; ++rt)
          #pragma unroll
          for (int nt = 0; nt < 4; ++nt) {
            const int wsel = ch * 2 + (nt >> 1);
            const int bitpos = (nt & 1) * 16 + col;
            #pragma unroll
            for (int reg = 0; reg < 4; ++reg) {
              const unsigned int w = ((const unsigned int*)&pw[rt][reg])[wsel];
              const float d = acc[rt][nt][reg];
              lacc[rt][reg] += exp2f(fmaf(d, C_EXP, -C_EXP));
              if ((w >> bitpos) & 1) Sacc[rt][reg] += d;
            }
          }
      } else {
        const bool left = (half == 0);
        #pragma unroll
        for (int rt = 0; rt < 2; ++rt)
          #pragma unroll
          for (int nt = 0; nt < 4; ++nt) {
            const int joff = ch * 64 + nt * 16 + col;   // 0..127 within tile
            const int jc = jbase + joff;
            const int wsel = joff >> 5;
            const int bitpos = joff & 31;
            #pragma unroll
            for (int reg = 0; reg < 4; ++reg) {
              const int i = ibase + swr + rt * 16 + quad * 4 + reg;
              const unsigned int w = ((const unsigned int*)&pw[rt][reg])[wsel];
              const float d = acc[rt][nt][reg];
              const bool bit = (w >> bitpos) & 1;
              const bool self = left && (jc == i);
              const bool pos = left ? (bit && !self) : (bit || (jc == i));
              const float e = exp2f(fmaf(d, C_EXP, -C_EXP));
              if (!self) lacc[rt][reg] += e;
              if (pos) { Sacc[rt][reg] += d; Pcnt[rt][reg] += 1.0f; }
            }
          }
      }
    }
  }

  // ---- reduce across the 16 col-lanes, atomically accumulate per-anchor ----
  #pragma unroll
  for (int rt = 0; rt < 2; ++rt)
    #pragma unroll
    for (int reg = 0; reg < 4; ++reg) {
      float l = lacc[rt][reg], S = Sacc[rt][reg], P = Pcnt[rt][reg];
      #pragma unroll
      for (int m = 1; m < 16; m <<= 1) {
        l += __shfl_xor(l, m);
        S += __shfl_xor(S, m);
        if (diag) P += __shfl_xor(P, m);
      }
      if (col == 0) {
        const int i = ibase + swr + rt * 16 + quad * 4 + reg;
        if (!diag) {
          const uint4 w = pw[rt][reg];
          P = 2.0f * (float)(__popc(w.x) + __popc(w.y) + __popc(w.z) + __popc(w.w));
        }
        atomicAdd(&part[i], l);
        atomicAdd(&part[4096 + i], S);
        atomicAdd(&part[8192 + i], P);
      }
    }
}

// ---------------- kernel 3: per-anchor loss + atomic final reduce ----------------
__global__ __launch_bounds__(128) void k_loss(
    const float* __restrict__ part, float* __restrict__ out)
{
  const int a = blockIdx.x * 128 + threadIdx.x;   // 0..4095
  const float l = part[a];
  const float S = part[4096 + a];
  const float P = part[8192 + a];
  const float np = fmaxf(P, 1.0f);
  float v = INV_TAU + logf(l + 1e-8f) - (S * INV_TAU) / np;
  #pragma unroll
  for (int off = 32; off > 0; off >>= 1) v += __shfl_xor(v, off);
  __shared__ float ws2[2];
  const int wave = threadIdx.x >> 6, lane = threadIdx.x & 63;
  if (lane == 0) ws2[wave] = v;
  __syncthreads();
  if (threadIdx.x == 0) atomicAdd(out, (ws2[0] + ws2[1]) * (1.0f / (float)N_ROWS));
}

extern "C" void kernel_launch(void* const* d_in, const int* in_sizes, int n_in,
                              void* d_out, int out_size, void* d_ws, size_t ws_size,
                              hipStream_t stream) {
  const float* z1 = (const float*)d_in[0];
  const float* z2 = (const float*)d_in[1];
  const int* labels = (const int*)d_in[2];
  float* out = (float*)d_out;
  char* ws = (char*)d_ws;

  unsigned int* zbf    = (unsigned int*)(ws);
  uint2* labs8         = (uint2*)(ws + 2097152);
  int* s               = (int*)(ws + 4194304);
  float* part          = (float*)(ws + 4210688);

  hipLaunchKernelGGL(k_norm_pack, dim3(2048), dim3(256), 0, stream,
                     z1, z2, labels, zbf, labs8, s, part, out);
  hipLaunchKernelGGL(k_fused, dim3(32, 32), dim3(256), 0, stream,
                     (const unsigned char*)labs8, s, (const unsigned short*)zbf, part);
  hipLaunchKernelGGL(k_loss, dim3(32), dim3(128), 0, stream, part, out);
}